// Round 20
// baseline (456.127 us; speedup 1.0000x reference)
//
#include <hip/hip_runtime.h>
#include <hip/hip_bf16.h>
#include <math.h>

constexpr int N    = 50000;
constexpr int NE   = 500000;
constexpr int IN   = 128;
constexpr int H    = 8;
constexpr int D    = 16;
constexpr int DSEM = 4;
constexpr int KS   = 21;
constexpr float CLAMP = 5.0f;

typedef __attribute__((ext_vector_type(8))) __bf16 bf16x8;
typedef __attribute__((ext_vector_type(4))) float  f32x4;

__device__ inline f32x4 mfma16(bf16x8 a, bf16x8 b, f32x4 c) {
    return __builtin_amdgcn_mfma_f32_16x16x32_bf16(a, b, c, 0, 0, 0);
}

__device__ inline void split_bf16(float f, unsigned& hi, unsigned& lo) {
    unsigned u = __float_as_uint(f);
    hi = (u + 0x7FFFu + ((u >> 16) & 1u)) >> 16;
    float fl = f - __uint_as_float(hi << 16);
    unsigned ul = __float_as_uint(fl);
    lo = (ul + 0x7FFFu + ((ul >> 16) & 1u)) >> 16;
}

__device__ inline void split2(float a, float b, unsigned& hi, unsigned& lo) {
    unsigned ha, la, hb, lb;
    split_bf16(a, ha, la);
    split_bf16(b, hb, lb);
    hi = ha | (hb << 16);
    lo = la | (lb << 16);
}

__device__ inline ushort f2bf(float f) {
    unsigned u = __float_as_uint(f);
    return (ushort)((u + 0x7FFFu + ((u >> 16) & 1u)) >> 16);
}
__device__ inline float bf2f(ushort u) {
    return __uint_as_float(((unsigned)u) << 16);
}
// unpack packed-2x-bf16 word: .x = elem at lower address, .y = upper
__device__ inline float2 bf2x(unsigned u) {
    return make_float2(__uint_as_float(u << 16), __uint_as_float(u & 0xFFFF0000u));
}

// ---------------------------------------------------------------------------
// prep_w: split [Ew (256 rows); wew (8 rows); zeros (8 rows)] = 272x128 into
// bf16 hi/lo, fragment-linear.  17 o-tiles.
// ---------------------------------------------------------------------------
__global__ __launch_bounds__(256) void prep_w_kernel(
    const float* __restrict__ Ew, const float* __restrict__ wew,
    ushort* __restrict__ EwHiF, ushort* __restrict__ EwLoF)
{
    int tid = blockIdx.x * 256 + threadIdx.x;          // 0..4351
    int l  = tid & 63;
    int ks = (tid >> 6) & 3;
    int ot = tid >> 8;                                 // 0..16
    int row = 16 * ot + (l & 15);
    int col = 32 * ks + 8 * (l >> 4);
    float4 f0, f1;
    if (row < 256) {
        const float* src = Ew + (size_t)row * 128 + col;
        f0 = *(const float4*)(src);
        f1 = *(const float4*)(src + 4);
    } else if (row < 264) {
        const float* src = wew + (size_t)(row - 256) * 128 + col;
        f0 = *(const float4*)(src);
        f1 = *(const float4*)(src + 4);
    } else {
        f0 = f1 = make_float4(0.f, 0.f, 0.f, 0.f);
    }
    unsigned H0,L0,H1,L1,H2,L2,H3,L3;
    split2(f0.x, f0.y, H0, L0);
    split2(f0.z, f0.w, H1, L1);
    split2(f1.x, f1.y, H2, L2);
    split2(f1.z, f1.w, H3, L3);
    *(uint4*)(EwHiF + (size_t)tid * 8) = make_uint4(H0, H1, H2, H3);
    *(uint4*)(EwLoF + (size_t)tid * 8) = make_uint4(L0, L1, L2, L3);
}

// ---------------------------------------------------------------------------
// prep_qkvw: split concat(Qw,Kw,Vw) (384x128) into bf16 hi/lo, frag-linear.
// ---------------------------------------------------------------------------
__global__ __launch_bounds__(256) void prep_qkvw_kernel(
    const float* __restrict__ Qw, const float* __restrict__ Kw,
    const float* __restrict__ Vw,
    ushort* __restrict__ WHiF, ushort* __restrict__ WLoF)
{
    int tid = blockIdx.x * 256 + threadIdx.x;          // 0..6143
    int l  = tid & 63;
    int ks = (tid >> 6) & 3;
    int ot = tid >> 8;                                 // 0..23
    int row = 16 * ot + (l & 15);                      // 0..383
    int col = 32 * ks + 8 * (l >> 4);
    const float* wrow = (row < 128) ? (Qw + (size_t)row * 128)
                      : (row < 256) ? (Kw + (size_t)(row - 128) * 128)
                                    : (Vw + (size_t)(row - 256) * 128);
    const float* src = wrow + col;
    float4 f0 = *(const float4*)(src);
    float4 f1 = *(const float4*)(src + 4);
    unsigned H0,L0,H1,L1,H2,L2,H3,L3;
    split2(f0.x, f0.y, H0, L0);
    split2(f0.z, f0.w, H1, L1);
    split2(f1.x, f1.y, H2, L2);
    split2(f1.z, f1.w, H3, L3);
    *(uint4*)(WHiF + (size_t)tid * 8) = make_uint4(H0, H1, H2, H3);
    *(uint4*)(WLoF + (size_t)tid * 8) = make_uint4(L0, L1, L2, L3);
}

// ---------------------------------------------------------------------------
// K1 v2: QKV split-bf16 MFMA + RoPE; Q,K,V epilogues sequential through one
// 32x132 buffer.  (round-16 known-good, unchanged)
// ---------------------------------------------------------------------------
constexpr int QNPB   = 32;
constexpr int QA_HI  = 0;
constexpr int QA_LO  = 8192;
constexpr int QSRR_OFF = 17024;
constexpr int QSC_OFF  = 20096;
constexpr int QSS_OFF  = 26240;
constexpr int Q_LDS    = 32384;
constexpr int QSO2_S   = 132;

__global__ __launch_bounds__(256, 3) void qkv_mfma_kernel(
    const float* __restrict__ x, const float* __restrict__ rrwp,
    const ushort* __restrict__ WHiF, const ushort* __restrict__ WLoF,
    const float* __restrict__ Qb, const float* __restrict__ Kb,
    const float* __restrict__ Vb, const float* __restrict__ Wang,
    float* __restrict__ Qh, float* __restrict__ Kh, ushort* __restrict__ Vh)
{
    __shared__ __align__(16) char smem[Q_LDS];

    const int t    = threadIdx.x;
    const int wid  = t >> 6;
    const int lane = t & 63;
    const int nb0  = blockIdx.x * QNPB;

    float* srr = (float*)(smem + QSRR_OFF);
    float* scc = (float*)(smem + QSC_OFF);
    float* sss = (float*)(smem + QSS_OFF);

    for (int i = t; i < QNPB * KS; i += 256) {
        int nl = i / KS, k = i % KS;
        int n = nb0 + nl;
        srr[nl * 24 + k] = (n < N) ? rrwp[(size_t)n * KS + k] : 0.0f;
    }

    {
        const int se = t >> 3, sq = t & 7;
        const int sn = nb0 + se;
        const int g = se >> 4, sr = se & 15;
        const int cs2 = sq >> 1, lb = 2 * (sq & 1);
        const int abase = ((g * 4 + cs2) * 64 + lb * 16 + sr) * 16;
        float4 v0, v1, v2, v3;
        if (sn < N) {
            const float4* ar = (const float4*)(x + (size_t)sn * 128 + sq * 16);
            v0 = ar[0]; v1 = ar[1]; v2 = ar[2]; v3 = ar[3];
        } else {
            v0 = v1 = v2 = v3 = make_float4(0.f, 0.f, 0.f, 0.f);
        }
        unsigned H0,L0,H1,L1,H2,L2,H3,L3,H4,L4,H5,L5,H6,L6,H7,L7;
        split2(v0.x, v0.y, H0, L0); split2(v0.z, v0.w, H1, L1);
        split2(v1.x, v1.y, H2, L2); split2(v1.z, v1.w, H3, L3);
        split2(v2.x, v2.y, H4, L4); split2(v2.z, v2.w, H5, L5);
        split2(v3.x, v3.y, H6, L6); split2(v3.z, v3.w, H7, L7);
        *(uint4*)(smem + QA_HI + abase)       = make_uint4(H0, H1, H2, H3);
        *(uint4*)(smem + QA_HI + abase + 256) = make_uint4(H4, H5, H6, H7);
        *(uint4*)(smem + QA_LO + abase)       = make_uint4(L0, L1, L2, L3);
        *(uint4*)(smem + QA_LO + abase + 256) = make_uint4(L4, L5, L6, L7);
    }
    __syncthreads();

    f32x4 acc[2][6];
    #pragma unroll
    for (int g = 0; g < 2; g++)
        #pragma unroll
        for (int o = 0; o < 6; o++)
            acc[g][o] = (f32x4){0.f, 0.f, 0.f, 0.f};

    #pragma unroll
    for (int cs2 = 0; cs2 < 4; cs2++) {
        bf16x8 Ah[2], Al[2];
        #pragma unroll
        for (int g = 0; g < 2; g++) {
            int off = ((g * 4 + cs2) * 64 + lane) * 16;
            Ah[g] = *(const bf16x8*)(smem + QA_HI + off);
            Al[g] = *(const bf16x8*)(smem + QA_LO + off);
        }
        #pragma unroll
        for (int otl = 0; otl < 6; otl++) {
            int ot = wid * 6 + otl;
            size_t woff = (size_t)((ot * 4 + cs2) * 64 + lane) * 16;
            bf16x8 Bh = *(const bf16x8*)((const char*)WHiF + woff);
            bf16x8 Bl = *(const bf16x8*)((const char*)WLoF + woff);
            #pragma unroll
            for (int g = 0; g < 2; g++) {
                acc[g][otl] = mfma16(Ah[g], Bh, acc[g][otl]);
                acc[g][otl] = mfma16(Al[g], Bh, acc[g][otl]);
                acc[g][otl] = mfma16(Ah[g], Bl, acc[g][otl]);
            }
        }
    }

    for (int i = t; i < QNPB * 48; i += 256) {
        int nl = i / 48, a = i % 48;
        int h = a / 6, r = a % 6;
        float av = 0.0f;
        #pragma unroll
        for (int k = 0; k < KS; k++)
            av = fmaf(srr[nl * 24 + k], Wang[(size_t)(h * KS + k) * 6 + r], av);
        float sv, cv;
        sincosf(av, &sv, &cv);
        scc[nl * 48 + a] = cv;
        sss[nl * 48 + a] = sv;
    }
    __syncthreads();

    float* sout2 = (float*)smem;
    const int lr4 = (lane >> 4) * 4;
    const int lc  = lane & 15;

    #pragma unroll 1
    for (int mat = 0; mat < 3; mat++) {
        #pragma unroll
        for (int otl = 0; otl < 6; otl++) {
            int tile = wid * 6 + otl;
            if (tile >= mat * 8 && tile < mat * 8 + 8) {
                int col = (tile - mat * 8) * 16 + lc;
                float bv = (mat == 0 ? Qb : mat == 1 ? Kb : Vb)[col];
                #pragma unroll
                for (int g = 0; g < 2; g++) {
                    int e = 16 * g + lr4;
                    #pragma unroll
                    for (int jr = 0; jr < 4; jr++)
                        sout2[(e + jr) * QSO2_S + col] = acc[g][otl][jr] + bv;
                }
            }
        }
        __syncthreads();

        #pragma unroll 1
        for (int r = 0; r < 16; r++) {
            int idx = r * 256 + t;
            int nl = idx >> 7, oo = idx & 127;
            int n = nb0 + nl;
            if (n >= N) continue;
            float val;
            int d = oo & 15;
            if (mat == 2 || d < DSEM) {
                val = sout2[nl * QSO2_S + oo];
            } else {
                int h = oo >> 4;
                int i2 = (d - DSEM) >> 1;
                float cv = scc[nl * 48 + h * 6 + i2];
                float sv = sss[nl * 48 + h * 6 + i2];
                int base = h * 16 + DSEM + 2 * i2;
                float xe = sout2[nl * QSO2_S + base];
                float xo = sout2[nl * QSO2_S + base + 1];
                val = ((d & 1) == 0) ? (xe * cv - xo * sv) : (xe * sv + xo * cv);
            }
            if (mat == 2)      Vh[(size_t)n * 128 + oo] = f2bf(val);
            else if (mat == 0) Qh[(size_t)n * 128 + oo] = val;
            else               Kh[(size_t)n * 128 + oo] = val;
        }
        __syncthreads();
    }
}

// ---------------------------------------------------------------------------
// K2 v11: R19 dual-chunk kernel + bank-conflict fixes:
//  - staging writes LANE-LINEAR (thread t writes LDS byte t*16 / 4096+t*16;
//    (edge, k-octet) re-derived from t so the fragment layout is identical)
//  - sOut row stride 288 -> 292 ushorts (4-row lane-group offset = 8 banks,
//    disjoint bank octets)
// ---------------------------------------------------------------------------
constexpr int EPB     = 32;
constexpr int AHI_OFF = 0;        // [2c][2g][2ks2][64][16B] = 8192
constexpr int ALO_OFF = 8192;     // ends 16384
constexpr int SOB_S   = 292;      // ushorts per edge row (8 heads x 36 + 4 pad)
constexpr int SOB_H   = 36;
constexpr int SBIAS_OFF = EPB * SOB_S * 2;            // 18688
constexpr int EDG_LDS   = SBIAS_OFF + EPB * 12 * 4;   // 20224

__global__ __launch_bounds__(256, 4) void edge_gemm_kernel(
    const float* __restrict__ edge_attr,
    const int* __restrict__ elist,
    const int* __restrict__ srcS, const int* __restrict__ dstS,
    const float* __restrict__ Qh, const float* __restrict__ Kh,
    const ushort* __restrict__ EwHiF, const ushort* __restrict__ EwLoF,
    const float* __restrict__ Eb, const float* __restrict__ web,
    float* __restrict__ wE, float* __restrict__ exS)
{
    __shared__ __align__(16) char smem[EDG_LDS];

    const int t    = threadIdx.x;
    const int wid  = t >> 6;
    const int lane = t & 63;
    const int eb0  = blockIdx.x * EPB;

    const int e_l = t >> 3;
    const int j8  = t & 7;
    const int pos = eb0 + e_l;
    const int ge   = elist[pos];
    const int sIdx = srcS[pos];
    const int dIdx = dstS[pos];

    f32x4 acc[2][4];
    #pragma unroll
    for (int g = 0; g < 2; g++)
        #pragma unroll
        for (int o = 0; o < 4; o++)
            acc[g][o] = (f32x4){0.f, 0.f, 0.f, 0.f};
    f32x4 accb[2];
    #pragma unroll
    for (int g = 0; g < 2; g++) accb[g] = (f32x4){0.f, 0.f, 0.f, 0.f};

    // ---- stage BOTH chunks, LANE-LINEAR LDS writes ----
    // thread t owns fragment slot t: SG2KS = t>>6 (= sg*2+ks2), lane = t&63,
    // lb = lane>>4 (k-octet), sr = lane&15 (edge within group).
    {
        const int SG2KS = t >> 6;
        const int sgS   = SG2KS >> 1;
        const int ks2S  = SG2KS & 1;
        const int lbS   = (t & 63) >> 4;
        const int srS   = t & 15;
        const int posS  = eb0 + sgS * 16 + srS;
        const int geS   = elist[posS];
        const float4* arS = (const float4*)(edge_attr + (size_t)geS * 128 + ks2S * 32 + lbS * 8);
        float4 a0 = arS[0], a1 = arS[1];      // chunk 0
        float4 b0 = arS[16], b1 = arS[17];    // chunk 1 (+64 floats)
        unsigned H0,L0,H1,L1,H2,L2,H3,L3;
        split2(a0.x, a0.y, H0, L0); split2(a0.z, a0.w, H1, L1);
        split2(a1.x, a1.y, H2, L2); split2(a1.z, a1.w, H3, L3);
        *(uint4*)(smem + AHI_OFF + t * 16) = make_uint4(H0, H1, H2, H3);
        *(uint4*)(smem + ALO_OFF + t * 16) = make_uint4(L0, L1, L2, L3);
        split2(b0.x, b0.y, H0, L0); split2(b0.z, b0.w, H1, L1);
        split2(b1.x, b1.y, H2, L2); split2(b1.z, b1.w, H3, L3);
        *(uint4*)(smem + AHI_OFF + 4096 + t * 16) = make_uint4(H0, H1, H2, H3);
        *(uint4*)(smem + ALO_OFF + 4096 + t * 16) = make_uint4(L0, L1, L2, L3);
    }
    __syncthreads();

    // ---- barrier-free MFMA over both chunks ----
    #pragma unroll 1
    for (int c = 0; c < 2; c++) {
        #pragma unroll
        for (int ks2 = 0; ks2 < 2; ks2++) {
            bf16x8 Wh[4], Wl[4];
            #pragma unroll
            for (int otl = 0; otl < 4; otl++) {
                int ot = wid * 4 + otl;
                size_t woff = (size_t)(((ot * 4 + c * 2 + ks2) * 64 + lane)) * 16;
                Wh[otl] = *(const bf16x8*)((const char*)EwHiF + woff);
                Wl[otl] = *(const bf16x8*)((const char*)EwLoF + woff);
            }
            bf16x8 Bbh, Bbl;
            if (wid == 0) {
                size_t woff = (size_t)(((16 * 4 + c * 2 + ks2) * 64 + lane)) * 16;
                Bbh = *(const bf16x8*)((const char*)EwHiF + woff);
                Bbl = *(const bf16x8*)((const char*)EwLoF + woff);
            }
            bf16x8 Ah[2], Al[2];
            #pragma unroll
            for (int g = 0; g < 2; g++) {
                // fragment slot: c major, then (g*2+ks2), then lane
                int off = (c * 4 + g * 2 + ks2) * 1024 + lane * 16;
                Ah[g] = *(const bf16x8*)(smem + AHI_OFF + off);
                Al[g] = *(const bf16x8*)(smem + ALO_OFF + off);
            }
            #pragma unroll
            for (int otl = 0; otl < 4; otl++) {
                #pragma unroll
                for (int g = 0; g < 2; g++) {
                    acc[g][otl] = mfma16(Ah[g], Wh[otl], acc[g][otl]);
                    acc[g][otl] = mfma16(Al[g], Wh[otl], acc[g][otl]);
                    acc[g][otl] = mfma16(Ah[g], Wl[otl], acc[g][otl]);
                }
            }
            if (wid == 0) {
                #pragma unroll
                for (int g = 0; g < 2; g++) {
                    accb[g] = mfma16(Ah[g], Bbh, accb[g]);
                    accb[g] = mfma16(Al[g], Bbh, accb[g]);
                    accb[g] = mfma16(Ah[g], Bbl, accb[g]);
                }
            }
        }
    }
    __syncthreads();    // all A reads done; sOut may overwrite A region

    // ---- early-issue epilogue K/Q gathers (hide under sOut phase) ----
    float4 kf[4], qf[4];
    {
        const float4* K4 = (const float4*)(Kh + (size_t)sIdx * 128);
        const float4* Q4 = (const float4*)(Qh + (size_t)dIdx * 128);
        #pragma unroll
        for (int j = 0; j < 4; j++) { kf[j] = K4[j8 * 4 + j]; qf[j] = Q4[j8 * 4 + j]; }
    }

    ushort* sOutB = (ushort*)smem;
    float*  sBias = (float*)(smem + SBIAS_OFF);
    const int lr4 = (lane >> 4) * 4;
    const int lc  = lane & 15;
    #pragma unroll
    for (int otl = 0; otl < 4; otl++) {
        int o = (wid * 4 + otl) * 16 + lc;
        int hh = o >> 5, col = o & 31;
        float ebv = Eb[o];
        #pragma unroll
        for (int g = 0; g < 2; g++) {
            int e = 16 * g + lr4;
            #pragma unroll
            for (int jr = 0; jr < 4; jr++)
                sOutB[(e + jr) * SOB_S + hh * SOB_H + col] = f2bf(acc[g][otl][jr] + ebv);
        }
    }
    if (wid == 0 && lc < 8) {
        float webv = web[lc];
        #pragma unroll
        for (int g = 0; g < 2; g++) {
            int e = 16 * g + lr4;
            #pragma unroll
            for (int jr = 0; jr < 4; jr++)
                sBias[(e + jr) * 12 + lc] = accb[g][jr] + webv;
        }
    }
    __syncthreads();

    // ---- per-(edge,head) epilogue ----
    {
        const int hh = j8;
        const float eb = sBias[e_l * 12 + hh];
        const float inv_s4  = 0.5f;
        const float inv_s12 = 0.28867513459481288f;
        float sem = kf[0].x*qf[0].x + kf[0].y*qf[0].y + kf[0].z*qf[0].z + kf[0].w*qf[0].w;
        float stl = 0.0f;
        #pragma unroll
        for (int j = 1; j < 4; j++)
            stl += kf[j].x*qf[j].x + kf[j].y*qf[j].y + kf[j].z*qf[j].z + kf[j].w*qf[j].w;
        float logit = sem * inv_s4 + stl * inv_s12 + eb;
        logit = fminf(fmaxf(logit, -CLAMP), CLAMP);
        float ex = __expf(logit);
        exS[(size_t)pos * 8 + hh] = ex;
        const ushort* srow = sOutB + e_l * SOB_S + hh * SOB_H;
        #pragma unroll
        for (int u = 0; u < 4; u++) {
            ushort4 ua = *(const ushort4*)(srow + 4 * u);
            ushort4 ub = *(const ushort4*)(srow + 16 + 4 * u);
            float4 A = make_float4(bf2f(ua.x), bf2f(ua.y), bf2f(ua.z), bf2f(ua.w));
            float4 B = make_float4(bf2f(ub.x), bf2f(ub.y), bf2f(ub.z), bf2f(ub.w));
            float4 kq = make_float4(kf[u].x + qf[u].x, kf[u].y + qf[u].y,
                                    kf[u].z + qf[u].z, kf[u].w + qf[u].w);
            float4 o;
            float v;
            v = kq.x * A.x; o.x = copysignf(sqrtf(fabsf(v)), v) + B.x;
            v = kq.y * A.y; o.y = copysignf(sqrtf(fabsf(v)), v) + B.y;
            v = kq.z * A.z; o.z = copysignf(sqrtf(fabsf(v)), v) + B.z;
            v = kq.w * A.w; o.w = copysignf(sqrtf(fabsf(v)), v) + B.w;
            *(float4*)(wE + (size_t)ge * 128 + hh * 16 + 4 * u) = o;
        }
    }
}

// ---------------------------------------------------------------------------
// CSR build: count -> scan -> scatter (scatter emits elist/srcS/dstS)
// ---------------------------------------------------------------------------
__global__ __launch_bounds__(256) void count_kernel(
    const int* __restrict__ dstI, int* __restrict__ cnt)
{
    int e = blockIdx.x * 256 + threadIdx.x;
    if (e < NE) atomicAdd(&cnt[dstI[e]], 1);
}

__global__ __launch_bounds__(1024) void block_scan_kernel(
    const int* __restrict__ cnt, int* __restrict__ rowstart, int* __restrict__ bsum)
{
    __shared__ int sbuf[1024];
    const int b = blockIdx.x, t = threadIdx.x;
    const int i = b * 1024 + t;
    sbuf[t] = (i < N) ? cnt[i] : 0;
    __syncthreads();
    for (int off = 1; off < 1024; off <<= 1) {
        int xv = sbuf[t];
        int yv = (t >= off) ? sbuf[t - off] : 0;
        __syncthreads();
        sbuf[t] = xv + yv;
        __syncthreads();
    }
    if (i < N) rowstart[i + 1] = sbuf[t];
    if (t == 1023) bsum[b] = sbuf[1023];
}

__global__ void scan_totals_kernel(int* __restrict__ bsum, int nb)
{
    if (threadIdx.x == 0 && blockIdx.x == 0) {
        int run = 0;
        for (int b = 0; b < nb; b++) { int v = bsum[b]; bsum[b] = run; run += v; }
    }
}

__global__ __launch_bounds__(1024) void add_offsets_kernel(
    const int* __restrict__ bsum, int* __restrict__ rowstart)
{
    const int b = blockIdx.x, t = threadIdx.x;
    const int i = b * 1024 + t;
    if (i < N) rowstart[i + 1] += bsum[b];
    if (b == 0 && t == 0) rowstart[0] = 0;
}

__global__ __launch_bounds__(256) void scatter_kernel(
    const int* __restrict__ srcI, const int* __restrict__ dstI,
    const int* __restrict__ rowstart, int* __restrict__ cursor,
    int* __restrict__ elist, int* __restrict__ srcS, int* __restrict__ dstS)
{
    int e = blockIdx.x * 256 + threadIdx.x;
    if (e >= NE) return;
    int d = dstI[e];
    int pos = rowstart[d] + atomicAdd(&cursor[d], 1);
    elist[pos] = e;
    srcS[pos]  = srcI[e];
    dstS[pos]  = d;
}

// ---------------------------------------------------------------------------
// K3 v2: gather-based wV — thread = (dst, 8-col group); uint4 bf16x8 V loads.
// ---------------------------------------------------------------------------
__global__ __launch_bounds__(256) void wv_kernel(
    const int* __restrict__ srcS, const int* __restrict__ rowstart,
    const ushort* __restrict__ Vh, const float* __restrict__ exS,
    float* __restrict__ wV)
{
    const int dd = blockIdx.x * 16 + (threadIdx.x >> 4);
    const int cg = threadIdx.x & 15;
    const int o0 = cg * 8;
    const int h  = o0 >> 4;
    const int st = rowstart[dd];
    const int en = rowstart[dd + 1];
    float den = 0.0f;
    float num[8];
    #pragma unroll
    for (int j = 0; j < 8; j++) num[j] = 0.0f;

    int i = st;
    for (; i + 2 <= en; i += 2) {
        int s0 = srcS[i], s1 = srcS[i + 1];
        float ex0 = exS[(size_t)i * 8 + h];
        float ex1 = exS[(size_t)(i + 1) * 8 + h];
        uint4 v0 = *(const uint4*)(Vh + (size_t)s0 * 128 + o0);
        uint4 v1 = *(const uint4*)(Vh + (size_t)s1 * 128 + o0);
        float2 p;
        p = bf2x(v0.x); num[0] = fmaf(p.x, ex0, num[0]); num[1] = fmaf(p.y, ex0, num[1]);
        p = bf2x(v0.y); num[2] = fmaf(p.x, ex0, num[2]); num[3] = fmaf(p.y, ex0, num[3]);
        p = bf2x(v0.z); num[4] = fmaf(p.x, ex0, num[4]); num[5] = fmaf(p.y, ex0, num[5]);
        p = bf2x(v0.w); num[6] = fmaf(p.x, ex0, num[6]); num[7] = fmaf(p.y, ex0, num[7]);
        p = bf2x(v1.x); num[0] = fmaf(p.x, ex1, num[0]); num[1] = fmaf(p.y, ex1, num[1]);
        p = bf2x(v1.y); num[2] = fmaf(p.x, ex1, num[2]); num[3] = fmaf(p.y, ex1, num[3]);
        p = bf2x(v1.z); num[4] = fmaf(p.x, ex1, num[4]); num[5] = fmaf(p.y, ex1, num[5]);
        p = bf2x(v1.w); num[6] = fmaf(p.x, ex1, num[6]); num[7] = fmaf(p.y, ex1, num[7]);
        den += ex0 + ex1;
    }
    if (i < en) {
        int s0 = srcS[i];
        float ex0 = exS[(size_t)i * 8 + h];
        uint4 v0 = *(const uint4*)(Vh + (size_t)s0 * 128 + o0);
        float2 p;
        p = bf2x(v0.x); num[0] = fmaf(p.x, ex0, num[0]); num[1] = fmaf(p.y, ex0, num[1]);
        p = bf2x(v0.y); num[2] = fmaf(p.x, ex0, num[2]); num[3] = fmaf(p.y, ex0, num[3]);
        p = bf2x(v0.z); num[4] = fmaf(p.x, ex0, num[4]); num[5] = fmaf(p.y, ex0, num[5]);
        p = bf2x(v0.w); num[6] = fmaf(p.x, ex0, num[6]); num[7] = fmaf(p.y, ex0, num[7]);
        den += ex0;
    }
    float inv = 1.0f / (den + 1e-16f);
    float4 o0v = make_float4(num[0]*inv, num[1]*inv, num[2]*inv, num[3]*inv);
    float4 o1v = make_float4(num[4]*inv, num[5]*inv, num[6]*inv, num[7]*inv);
    *(float4*)(wV + (size_t)dd * 128 + o0)     = o0v;
    *(float4*)(wV + (size_t)dd * 128 + o0 + 4) = o1v;
}

// ---------------------------------------------------------------------------
extern "C" void kernel_launch(void* const* d_in, const int* in_sizes, int n_in,
                              void* d_out, int out_size, void* d_ws, size_t ws_size,
                              hipStream_t stream)
{
    const float* x         = (const float*)d_in[0];
    const int*   edge_idx  = (const int*)d_in[1];
    const float* rrwp      = (const float*)d_in[2];
    const float* edge_attr = (const float*)d_in[3];
    const float* Qw        = (const float*)d_in[4];
    const float* Qb        = (const float*)d_in[5];
    const float* Kw        = (const float*)d_in[6];
    const float* Kb        = (const float*)d_in[7];
    const float* Vw        = (const float*)d_in[8];
    const float* Vb        = (const float*)d_in[9];
    const float* Ew        = (const float*)d_in[10];
    const float* Eb        = (const float*)d_in[11];
    const float* wew       = (const float*)d_in[12];
    const float* web       = (const float*)d_in[13];
    const float* Wang      = (const float*)d_in[14];

    const int* srcI = edge_idx;
    const int* dstI = edge_idx + NE;

    float* wV = (float*)d_out;                       // N * 128
    float* wE = wV + (size_t)N * 128;                // NE * 128

    ushort* EwHiF = (ushort*)d_ws;                   // 34816 bf16
    ushort* EwLoF = EwHiF + 34816;                   // 34816
    ushort* QWHiF = EwLoF + 34816;                   // 49152
    ushort* QWLoF = QWHiF + 49152;                   // 49152
    ushort* VhB = QWLoF + 49152;                     // N*128 bf16
    float* Qh   = (float*)(VhB + (size_t)N * 128);   // N*128 fp32
    float* Kh   = Qh + (size_t)N * 128;
    float* exS  = Kh + (size_t)N * 128;              // NE*8 (position-indexed)
    int* cnt      = (int*)(exS + (size_t)NE * 8);    // N
    int* rowstart = cnt + N;                         // N+1
    int* cursor   = rowstart + (N + 1);              // N
    int* elist    = cursor + N;                      // NE
    int* srcS     = elist + NE;                      // NE
    int* dstS     = srcS + NE;                       // NE
    int* bsum     = dstS + NE;                       // 64

    const int NB_SCAN = (N + 1023) / 1024;           // 49

    hipMemsetAsync(cnt, 0, (size_t)N * sizeof(int), stream);
    hipMemsetAsync(cursor, 0, (size_t)N * sizeof(int), stream);

    prep_w_kernel<<<17, 256, 0, stream>>>(Ew, wew, EwHiF, EwLoF);
    prep_qkvw_kernel<<<24, 256, 0, stream>>>(Qw, Kw, Vw, QWHiF, QWLoF);

    qkv_mfma_kernel<<<(N + QNPB - 1) / QNPB, 256, 0, stream>>>(
        x, rrwp, QWHiF, QWLoF, Qb, Kb, Vb, Wang, Qh, Kh, VhB);

    count_kernel<<<(NE + 255) / 256, 256, 0, stream>>>(dstI, cnt);
    block_scan_kernel<<<NB_SCAN, 1024, 0, stream>>>(cnt, rowstart, bsum);
    scan_totals_kernel<<<1, 64, 0, stream>>>(bsum, NB_SCAN);
    add_offsets_kernel<<<NB_SCAN, 1024, 0, stream>>>(bsum, rowstart);
    scatter_kernel<<<(NE + 255) / 256, 256, 0, stream>>>(
        srcI, dstI, rowstart, cursor, elist, srcS, dstS);

    edge_gemm_kernel<<<NE / EPB, 256, 0, stream>>>(
        edge_attr, elist, srcS, dstS, Qh, Kh, EwHiF, EwLoF, Eb, web, wE, exS);

    wv_kernel<<<N / 16, 256, 0, stream>>>(
        srcS, rowstart, VhB, exS, wV);
}

// Round 21
// 441.495 us; speedup vs baseline: 1.0331x; 1.0331x over previous
//
#include <hip/hip_runtime.h>
#include <hip/hip_bf16.h>
#include <math.h>

constexpr int N    = 50000;
constexpr int NE   = 500000;
constexpr int IN   = 128;
constexpr int H    = 8;
constexpr int D    = 16;
constexpr int DSEM = 4;
constexpr int KS   = 21;
constexpr float CLAMP = 5.0f;

typedef __attribute__((ext_vector_type(8))) __bf16 bf16x8;
typedef __attribute__((ext_vector_type(4))) float  f32x4;

__device__ inline f32x4 mfma16(bf16x8 a, bf16x8 b, f32x4 c) {
    return __builtin_amdgcn_mfma_f32_16x16x32_bf16(a, b, c, 0, 0, 0);
}

__device__ inline void split_bf16(float f, unsigned& hi, unsigned& lo) {
    unsigned u = __float_as_uint(f);
    hi = (u + 0x7FFFu + ((u >> 16) & 1u)) >> 16;
    float fl = f - __uint_as_float(hi << 16);
    unsigned ul = __float_as_uint(fl);
    lo = (ul + 0x7FFFu + ((ul >> 16) & 1u)) >> 16;
}

__device__ inline void split2(float a, float b, unsigned& hi, unsigned& lo) {
    unsigned ha, la, hb, lb;
    split_bf16(a, ha, la);
    split_bf16(b, hb, lb);
    hi = ha | (hb << 16);
    lo = la | (lb << 16);
}

__device__ inline ushort f2bf(float f) {
    unsigned u = __float_as_uint(f);
    return (ushort)((u + 0x7FFFu + ((u >> 16) & 1u)) >> 16);
}
__device__ inline float bf2f(ushort u) {
    return __uint_as_float(((unsigned)u) << 16);
}
// unpack packed-2x-bf16 word: .x = elem at lower address, .y = upper
__device__ inline float2 bf2x(unsigned u) {
    return make_float2(__uint_as_float(u << 16), __uint_as_float(u & 0xFFFF0000u));
}

// ---------------------------------------------------------------------------
// prep_w: split [Ew (256 rows); wew (8 rows); zeros (8 rows)] = 272x128 into
// bf16 hi/lo, fragment-linear.  17 o-tiles.
// ---------------------------------------------------------------------------
__global__ __launch_bounds__(256) void prep_w_kernel(
    const float* __restrict__ Ew, const float* __restrict__ wew,
    ushort* __restrict__ EwHiF, ushort* __restrict__ EwLoF)
{
    int tid = blockIdx.x * 256 + threadIdx.x;          // 0..4351
    int l  = tid & 63;
    int ks = (tid >> 6) & 3;
    int ot = tid >> 8;                                 // 0..16
    int row = 16 * ot + (l & 15);
    int col = 32 * ks + 8 * (l >> 4);
    float4 f0, f1;
    if (row < 256) {
        const float* src = Ew + (size_t)row * 128 + col;
        f0 = *(const float4*)(src);
        f1 = *(const float4*)(src + 4);
    } else if (row < 264) {
        const float* src = wew + (size_t)(row - 256) * 128 + col;
        f0 = *(const float4*)(src);
        f1 = *(const float4*)(src + 4);
    } else {
        f0 = f1 = make_float4(0.f, 0.f, 0.f, 0.f);
    }
    unsigned H0,L0,H1,L1,H2,L2,H3,L3;
    split2(f0.x, f0.y, H0, L0);
    split2(f0.z, f0.w, H1, L1);
    split2(f1.x, f1.y, H2, L2);
    split2(f1.z, f1.w, H3, L3);
    *(uint4*)(EwHiF + (size_t)tid * 8) = make_uint4(H0, H1, H2, H3);
    *(uint4*)(EwLoF + (size_t)tid * 8) = make_uint4(L0, L1, L2, L3);
}

// ---------------------------------------------------------------------------
// prep_qkvw: split concat(Qw,Kw,Vw) (384x128) into bf16 hi/lo, frag-linear.
// ---------------------------------------------------------------------------
__global__ __launch_bounds__(256) void prep_qkvw_kernel(
    const float* __restrict__ Qw, const float* __restrict__ Kw,
    const float* __restrict__ Vw,
    ushort* __restrict__ WHiF, ushort* __restrict__ WLoF)
{
    int tid = blockIdx.x * 256 + threadIdx.x;          // 0..6143
    int l  = tid & 63;
    int ks = (tid >> 6) & 3;
    int ot = tid >> 8;                                 // 0..23
    int row = 16 * ot + (l & 15);                      // 0..383
    int col = 32 * ks + 8 * (l >> 4);
    const float* wrow = (row < 128) ? (Qw + (size_t)row * 128)
                      : (row < 256) ? (Kw + (size_t)(row - 128) * 128)
                                    : (Vw + (size_t)(row - 256) * 128);
    const float* src = wrow + col;
    float4 f0 = *(const float4*)(src);
    float4 f1 = *(const float4*)(src + 4);
    unsigned H0,L0,H1,L1,H2,L2,H3,L3;
    split2(f0.x, f0.y, H0, L0);
    split2(f0.z, f0.w, H1, L1);
    split2(f1.x, f1.y, H2, L2);
    split2(f1.z, f1.w, H3, L3);
    *(uint4*)(WHiF + (size_t)tid * 8) = make_uint4(H0, H1, H2, H3);
    *(uint4*)(WLoF + (size_t)tid * 8) = make_uint4(L0, L1, L2, L3);
}

// ---------------------------------------------------------------------------
// K1 v2: QKV split-bf16 MFMA + RoPE; Q,K,V epilogues sequential through one
// 32x132 buffer.  (round-16 known-good, unchanged)
// ---------------------------------------------------------------------------
constexpr int QNPB   = 32;
constexpr int QA_HI  = 0;
constexpr int QA_LO  = 8192;
constexpr int QSRR_OFF = 17024;
constexpr int QSC_OFF  = 20096;
constexpr int QSS_OFF  = 26240;
constexpr int Q_LDS    = 32384;
constexpr int QSO2_S   = 132;

__global__ __launch_bounds__(256, 3) void qkv_mfma_kernel(
    const float* __restrict__ x, const float* __restrict__ rrwp,
    const ushort* __restrict__ WHiF, const ushort* __restrict__ WLoF,
    const float* __restrict__ Qb, const float* __restrict__ Kb,
    const float* __restrict__ Vb, const float* __restrict__ Wang,
    float* __restrict__ Qh, float* __restrict__ Kh, ushort* __restrict__ Vh)
{
    __shared__ __align__(16) char smem[Q_LDS];

    const int t    = threadIdx.x;
    const int wid  = t >> 6;
    const int lane = t & 63;
    const int nb0  = blockIdx.x * QNPB;

    float* srr = (float*)(smem + QSRR_OFF);
    float* scc = (float*)(smem + QSC_OFF);
    float* sss = (float*)(smem + QSS_OFF);

    for (int i = t; i < QNPB * KS; i += 256) {
        int nl = i / KS, k = i % KS;
        int n = nb0 + nl;
        srr[nl * 24 + k] = (n < N) ? rrwp[(size_t)n * KS + k] : 0.0f;
    }

    {
        const int se = t >> 3, sq = t & 7;
        const int sn = nb0 + se;
        const int g = se >> 4, sr = se & 15;
        const int cs2 = sq >> 1, lb = 2 * (sq & 1);
        const int abase = ((g * 4 + cs2) * 64 + lb * 16 + sr) * 16;
        float4 v0, v1, v2, v3;
        if (sn < N) {
            const float4* ar = (const float4*)(x + (size_t)sn * 128 + sq * 16);
            v0 = ar[0]; v1 = ar[1]; v2 = ar[2]; v3 = ar[3];
        } else {
            v0 = v1 = v2 = v3 = make_float4(0.f, 0.f, 0.f, 0.f);
        }
        unsigned H0,L0,H1,L1,H2,L2,H3,L3,H4,L4,H5,L5,H6,L6,H7,L7;
        split2(v0.x, v0.y, H0, L0); split2(v0.z, v0.w, H1, L1);
        split2(v1.x, v1.y, H2, L2); split2(v1.z, v1.w, H3, L3);
        split2(v2.x, v2.y, H4, L4); split2(v2.z, v2.w, H5, L5);
        split2(v3.x, v3.y, H6, L6); split2(v3.z, v3.w, H7, L7);
        *(uint4*)(smem + QA_HI + abase)       = make_uint4(H0, H1, H2, H3);
        *(uint4*)(smem + QA_HI + abase + 256) = make_uint4(H4, H5, H6, H7);
        *(uint4*)(smem + QA_LO + abase)       = make_uint4(L0, L1, L2, L3);
        *(uint4*)(smem + QA_LO + abase + 256) = make_uint4(L4, L5, L6, L7);
    }
    __syncthreads();

    f32x4 acc[2][6];
    #pragma unroll
    for (int g = 0; g < 2; g++)
        #pragma unroll
        for (int o = 0; o < 6; o++)
            acc[g][o] = (f32x4){0.f, 0.f, 0.f, 0.f};

    #pragma unroll
    for (int cs2 = 0; cs2 < 4; cs2++) {
        bf16x8 Ah[2], Al[2];
        #pragma unroll
        for (int g = 0; g < 2; g++) {
            int off = ((g * 4 + cs2) * 64 + lane) * 16;
            Ah[g] = *(const bf16x8*)(smem + QA_HI + off);
            Al[g] = *(const bf16x8*)(smem + QA_LO + off);
        }
        #pragma unroll
        for (int otl = 0; otl < 6; otl++) {
            int ot = wid * 6 + otl;
            size_t woff = (size_t)((ot * 4 + cs2) * 64 + lane) * 16;
            bf16x8 Bh = *(const bf16x8*)((const char*)WHiF + woff);
            bf16x8 Bl = *(const bf16x8*)((const char*)WLoF + woff);
            #pragma unroll
            for (int g = 0; g < 2; g++) {
                acc[g][otl] = mfma16(Ah[g], Bh, acc[g][otl]);
                acc[g][otl] = mfma16(Al[g], Bh, acc[g][otl]);
                acc[g][otl] = mfma16(Ah[g], Bl, acc[g][otl]);
            }
        }
    }

    for (int i = t; i < QNPB * 48; i += 256) {
        int nl = i / 48, a = i % 48;
        int h = a / 6, r = a % 6;
        float av = 0.0f;
        #pragma unroll
        for (int k = 0; k < KS; k++)
            av = fmaf(srr[nl * 24 + k], Wang[(size_t)(h * KS + k) * 6 + r], av);
        float sv, cv;
        sincosf(av, &sv, &cv);
        scc[nl * 48 + a] = cv;
        sss[nl * 48 + a] = sv;
    }
    __syncthreads();

    float* sout2 = (float*)smem;
    const int lr4 = (lane >> 4) * 4;
    const int lc  = lane & 15;

    #pragma unroll 1
    for (int mat = 0; mat < 3; mat++) {
        #pragma unroll
        for (int otl = 0; otl < 6; otl++) {
            int tile = wid * 6 + otl;
            if (tile >= mat * 8 && tile < mat * 8 + 8) {
                int col = (tile - mat * 8) * 16 + lc;
                float bv = (mat == 0 ? Qb : mat == 1 ? Kb : Vb)[col];
                #pragma unroll
                for (int g = 0; g < 2; g++) {
                    int e = 16 * g + lr4;
                    #pragma unroll
                    for (int jr = 0; jr < 4; jr++)
                        sout2[(e + jr) * QSO2_S + col] = acc[g][otl][jr] + bv;
                }
            }
        }
        __syncthreads();

        #pragma unroll 1
        for (int r = 0; r < 16; r++) {
            int idx = r * 256 + t;
            int nl = idx >> 7, oo = idx & 127;
            int n = nb0 + nl;
            if (n >= N) continue;
            float val;
            int d = oo & 15;
            if (mat == 2 || d < DSEM) {
                val = sout2[nl * QSO2_S + oo];
            } else {
                int h = oo >> 4;
                int i2 = (d - DSEM) >> 1;
                float cv = scc[nl * 48 + h * 6 + i2];
                float sv = sss[nl * 48 + h * 6 + i2];
                int base = h * 16 + DSEM + 2 * i2;
                float xe = sout2[nl * QSO2_S + base];
                float xo = sout2[nl * QSO2_S + base + 1];
                val = ((d & 1) == 0) ? (xe * cv - xo * sv) : (xe * sv + xo * cv);
            }
            if (mat == 2)      Vh[(size_t)n * 128 + oo] = f2bf(val);
            else if (mat == 0) Qh[(size_t)n * 128 + oo] = val;
            else               Kh[(size_t)n * 128 + oo] = val;
        }
        __syncthreads();
    }
}

// ---------------------------------------------------------------------------
// K2 v12: R19 dual-chunk kernel (coalesced staging, known 249.5 us) with
// ONLY the sOut row stride 288 -> 292 pad (removes 4-way sOut write
// aliasing; independent of staging layout).
// ---------------------------------------------------------------------------
constexpr int EPB     = 32;
constexpr int AHI_OFF = 0;        // [2c][2g][2ks2][64][16B] = 8192
constexpr int ALO_OFF = 8192;     // ends 16384
constexpr int SOB_S   = 292;      // ushorts per edge row (8 heads x 36 + 4 pad)
constexpr int SOB_H   = 36;
constexpr int SBIAS_OFF = EPB * SOB_S * 2;            // 18688
constexpr int EDG_LDS   = SBIAS_OFF + EPB * 12 * 4;   // 20224

__global__ __launch_bounds__(256, 4) void edge_gemm_kernel(
    const float* __restrict__ edge_attr,
    const int* __restrict__ elist,
    const int* __restrict__ srcS, const int* __restrict__ dstS,
    const float* __restrict__ Qh, const float* __restrict__ Kh,
    const ushort* __restrict__ EwHiF, const ushort* __restrict__ EwLoF,
    const float* __restrict__ Eb, const float* __restrict__ web,
    float* __restrict__ wE, float* __restrict__ exS)
{
    __shared__ __align__(16) char smem[EDG_LDS];

    const int t    = threadIdx.x;
    const int wid  = t >> 6;
    const int lane = t & 63;
    const int eb0  = blockIdx.x * EPB;

    const int e_l = t >> 3;
    const int j8  = t & 7;
    const int pos = eb0 + e_l;
    const int ge   = elist[pos];
    const int sIdx = srcS[pos];
    const int dIdx = dstS[pos];

    const int sg    = e_l >> 4;
    const int sks2  = j8 >> 2;
    const int slane = (j8 & 3) * 16 + (e_l & 15);
    // chunk-c A-frag base: [c][g][ks2] major order
    const int abase0 = ((sg * 2 + sks2) * 64 + slane) * 16;          // c=0
    const int abase1 = abase0 + 4096;                                // c=1

    f32x4 acc[2][4];
    #pragma unroll
    for (int g = 0; g < 2; g++)
        #pragma unroll
        for (int o = 0; o < 4; o++)
            acc[g][o] = (f32x4){0.f, 0.f, 0.f, 0.f};
    f32x4 accb[2];
    #pragma unroll
    for (int g = 0; g < 2; g++) accb[g] = (f32x4){0.f, 0.f, 0.f, 0.f};

    // ---- stage BOTH chunks (all 4 global loads issue together; coalesced) --
    {
        const float4* ar = (const float4*)(edge_attr + (size_t)ge * 128 + j8 * 8);
        float4 a0 = ar[0], a1 = ar[1];        // chunk 0
        float4 b0 = ar[16], b1 = ar[17];      // chunk 1 (+64 floats)
        unsigned H0,L0,H1,L1,H2,L2,H3,L3;
        split2(a0.x, a0.y, H0, L0); split2(a0.z, a0.w, H1, L1);
        split2(a1.x, a1.y, H2, L2); split2(a1.z, a1.w, H3, L3);
        *(uint4*)(smem + AHI_OFF + abase0) = make_uint4(H0, H1, H2, H3);
        *(uint4*)(smem + ALO_OFF + abase0) = make_uint4(L0, L1, L2, L3);
        split2(b0.x, b0.y, H0, L0); split2(b0.z, b0.w, H1, L1);
        split2(b1.x, b1.y, H2, L2); split2(b1.z, b1.w, H3, L3);
        *(uint4*)(smem + AHI_OFF + abase1) = make_uint4(H0, H1, H2, H3);
        *(uint4*)(smem + ALO_OFF + abase1) = make_uint4(L0, L1, L2, L3);
    }
    __syncthreads();

    // ---- barrier-free MFMA over both chunks ----
    #pragma unroll 1
    for (int c = 0; c < 2; c++) {
        #pragma unroll
        for (int ks2 = 0; ks2 < 2; ks2++) {
            bf16x8 Wh[4], Wl[4];
            #pragma unroll
            for (int otl = 0; otl < 4; otl++) {
                int ot = wid * 4 + otl;
                size_t woff = (size_t)(((ot * 4 + c * 2 + ks2) * 64 + lane)) * 16;
                Wh[otl] = *(const bf16x8*)((const char*)EwHiF + woff);
                Wl[otl] = *(const bf16x8*)((const char*)EwLoF + woff);
            }
            bf16x8 Bbh, Bbl;
            if (wid == 0) {
                size_t woff = (size_t)(((16 * 4 + c * 2 + ks2) * 64 + lane)) * 16;
                Bbh = *(const bf16x8*)((const char*)EwHiF + woff);
                Bbl = *(const bf16x8*)((const char*)EwLoF + woff);
            }
            bf16x8 Ah[2], Al[2];
            #pragma unroll
            for (int g = 0; g < 2; g++) {
                int off = (((c * 2 + g) * 2 + ks2) * 64 + lane) * 16;
                Ah[g] = *(const bf16x8*)(smem + AHI_OFF + off);
                Al[g] = *(const bf16x8*)(smem + ALO_OFF + off);
            }
            #pragma unroll
            for (int otl = 0; otl < 4; otl++) {
                #pragma unroll
                for (int g = 0; g < 2; g++) {
                    acc[g][otl] = mfma16(Ah[g], Wh[otl], acc[g][otl]);
                    acc[g][otl] = mfma16(Al[g], Wh[otl], acc[g][otl]);
                    acc[g][otl] = mfma16(Ah[g], Wl[otl], acc[g][otl]);
                }
            }
            if (wid == 0) {
                #pragma unroll
                for (int g = 0; g < 2; g++) {
                    accb[g] = mfma16(Ah[g], Bbh, accb[g]);
                    accb[g] = mfma16(Al[g], Bbh, accb[g]);
                    accb[g] = mfma16(Ah[g], Bbl, accb[g]);
                }
            }
        }
    }
    __syncthreads();    // all A reads done; sOut may overwrite A region

    // ---- early-issue epilogue K/Q gathers (hide under sOut phase) ----
    float4 kf[4], qf[4];
    {
        const float4* K4 = (const float4*)(Kh + (size_t)sIdx * 128);
        const float4* Q4 = (const float4*)(Qh + (size_t)dIdx * 128);
        #pragma unroll
        for (int j = 0; j < 4; j++) { kf[j] = K4[j8 * 4 + j]; qf[j] = Q4[j8 * 4 + j]; }
    }

    ushort* sOutB = (ushort*)smem;
    float*  sBias = (float*)(smem + SBIAS_OFF);
    const int lr4 = (lane >> 4) * 4;
    const int lc  = lane & 15;
    #pragma unroll
    for (int otl = 0; otl < 4; otl++) {
        int o = (wid * 4 + otl) * 16 + lc;
        int hh = o >> 5, col = o & 31;
        float ebv = Eb[o];
        #pragma unroll
        for (int g = 0; g < 2; g++) {
            int e = 16 * g + lr4;
            #pragma unroll
            for (int jr = 0; jr < 4; jr++)
                sOutB[(e + jr) * SOB_S + hh * SOB_H + col] = f2bf(acc[g][otl][jr] + ebv);
        }
    }
    if (wid == 0 && lc < 8) {
        float webv = web[lc];
        #pragma unroll
        for (int g = 0; g < 2; g++) {
            int e = 16 * g + lr4;
            #pragma unroll
            for (int jr = 0; jr < 4; jr++)
                sBias[(e + jr) * 12 + lc] = accb[g][jr] + webv;
        }
    }
    __syncthreads();

    // ---- per-(edge,head) epilogue ----
    {
        const int hh = j8;
        const float eb = sBias[e_l * 12 + hh];
        const float inv_s4  = 0.5f;
        const float inv_s12 = 0.28867513459481288f;
        float sem = kf[0].x*qf[0].x + kf[0].y*qf[0].y + kf[0].z*qf[0].z + kf[0].w*qf[0].w;
        float stl = 0.0f;
        #pragma unroll
        for (int j = 1; j < 4; j++)
            stl += kf[j].x*qf[j].x + kf[j].y*qf[j].y + kf[j].z*qf[j].z + kf[j].w*qf[j].w;
        float logit = sem * inv_s4 + stl * inv_s12 + eb;
        logit = fminf(fmaxf(logit, -CLAMP), CLAMP);
        float ex = __expf(logit);
        exS[(size_t)pos * 8 + hh] = ex;
        const ushort* srow = sOutB + e_l * SOB_S + hh * SOB_H;
        #pragma unroll
        for (int u = 0; u < 4; u++) {
            ushort4 ua = *(const ushort4*)(srow + 4 * u);
            ushort4 ub = *(const ushort4*)(srow + 16 + 4 * u);
            float4 A = make_float4(bf2f(ua.x), bf2f(ua.y), bf2f(ua.z), bf2f(ua.w));
            float4 B = make_float4(bf2f(ub.x), bf2f(ub.y), bf2f(ub.z), bf2f(ub.w));
            float4 kq = make_float4(kf[u].x + qf[u].x, kf[u].y + qf[u].y,
                                    kf[u].z + qf[u].z, kf[u].w + qf[u].w);
            float4 o;
            float v;
            v = kq.x * A.x; o.x = copysignf(sqrtf(fabsf(v)), v) + B.x;
            v = kq.y * A.y; o.y = copysignf(sqrtf(fabsf(v)), v) + B.y;
            v = kq.z * A.z; o.z = copysignf(sqrtf(fabsf(v)), v) + B.z;
            v = kq.w * A.w; o.w = copysignf(sqrtf(fabsf(v)), v) + B.w;
            *(float4*)(wE + (size_t)ge * 128 + hh * 16 + 4 * u) = o;
        }
    }
}

// ---------------------------------------------------------------------------
// CSR build: count -> scan -> scatter (scatter emits elist/srcS/dstS)
// ---------------------------------------------------------------------------
__global__ __launch_bounds__(256) void count_kernel(
    const int* __restrict__ dstI, int* __restrict__ cnt)
{
    int e = blockIdx.x * 256 + threadIdx.x;
    if (e < NE) atomicAdd(&cnt[dstI[e]], 1);
}

__global__ __launch_bounds__(1024) void block_scan_kernel(
    const int* __restrict__ cnt, int* __restrict__ rowstart, int* __restrict__ bsum)
{
    __shared__ int sbuf[1024];
    const int b = blockIdx.x, t = threadIdx.x;
    const int i = b * 1024 + t;
    sbuf[t] = (i < N) ? cnt[i] : 0;
    __syncthreads();
    for (int off = 1; off < 1024; off <<= 1) {
        int xv = sbuf[t];
        int yv = (t >= off) ? sbuf[t - off] : 0;
        __syncthreads();
        sbuf[t] = xv + yv;
        __syncthreads();
    }
    if (i < N) rowstart[i + 1] = sbuf[t];
    if (t == 1023) bsum[b] = sbuf[1023];
}

__global__ void scan_totals_kernel(int* __restrict__ bsum, int nb)
{
    if (threadIdx.x == 0 && blockIdx.x == 0) {
        int run = 0;
        for (int b = 0; b < nb; b++) { int v = bsum[b]; bsum[b] = run; run += v; }
    }
}

__global__ __launch_bounds__(1024) void add_offsets_kernel(
    const int* __restrict__ bsum, int* __restrict__ rowstart)
{
    const int b = blockIdx.x, t = threadIdx.x;
    const int i = b * 1024 + t;
    if (i < N) rowstart[i + 1] += bsum[b];
    if (b == 0 && t == 0) rowstart[0] = 0;
}

__global__ __launch_bounds__(256) void scatter_kernel(
    const int* __restrict__ srcI, const int* __restrict__ dstI,
    const int* __restrict__ rowstart, int* __restrict__ cursor,
    int* __restrict__ elist, int* __restrict__ srcS, int* __restrict__ dstS)
{
    int e = blockIdx.x * 256 + threadIdx.x;
    if (e >= NE) return;
    int d = dstI[e];
    int pos = rowstart[d] + atomicAdd(&cursor[d], 1);
    elist[pos] = e;
    srcS[pos]  = srcI[e];
    dstS[pos]  = d;
}

// ---------------------------------------------------------------------------
// K3 v2: gather-based wV — thread = (dst, 8-col group); uint4 bf16x8 V loads.
// ---------------------------------------------------------------------------
__global__ __launch_bounds__(256) void wv_kernel(
    const int* __restrict__ srcS, const int* __restrict__ rowstart,
    const ushort* __restrict__ Vh, const float* __restrict__ exS,
    float* __restrict__ wV)
{
    const int dd = blockIdx.x * 16 + (threadIdx.x >> 4);
    const int cg = threadIdx.x & 15;
    const int o0 = cg * 8;
    const int h  = o0 >> 4;
    const int st = rowstart[dd];
    const int en = rowstart[dd + 1];
    float den = 0.0f;
    float num[8];
    #pragma unroll
    for (int j = 0; j < 8; j++) num[j] = 0.0f;

    int i = st;
    for (; i + 2 <= en; i += 2) {
        int s0 = srcS[i], s1 = srcS[i + 1];
        float ex0 = exS[(size_t)i * 8 + h];
        float ex1 = exS[(size_t)(i + 1) * 8 + h];
        uint4 v0 = *(const uint4*)(Vh + (size_t)s0 * 128 + o0);
        uint4 v1 = *(const uint4*)(Vh + (size_t)s1 * 128 + o0);
        float2 p;
        p = bf2x(v0.x); num[0] = fmaf(p.x, ex0, num[0]); num[1] = fmaf(p.y, ex0, num[1]);
        p = bf2x(v0.y); num[2] = fmaf(p.x, ex0, num[2]); num[3] = fmaf(p.y, ex0, num[3]);
        p = bf2x(v0.z); num[4] = fmaf(p.x, ex0, num[4]); num[5] = fmaf(p.y, ex0, num[5]);
        p = bf2x(v0.w); num[6] = fmaf(p.x, ex0, num[6]); num[7] = fmaf(p.y, ex0, num[7]);
        p = bf2x(v1.x); num[0] = fmaf(p.x, ex1, num[0]); num[1] = fmaf(p.y, ex1, num[1]);
        p = bf2x(v1.y); num[2] = fmaf(p.x, ex1, num[2]); num[3] = fmaf(p.y, ex1, num[3]);
        p = bf2x(v1.z); num[4] = fmaf(p.x, ex1, num[4]); num[5] = fmaf(p.y, ex1, num[5]);
        p = bf2x(v1.w); num[6] = fmaf(p.x, ex1, num[6]); num[7] = fmaf(p.y, ex1, num[7]);
        den += ex0 + ex1;
    }
    if (i < en) {
        int s0 = srcS[i];
        float ex0 = exS[(size_t)i * 8 + h];
        uint4 v0 = *(const uint4*)(Vh + (size_t)s0 * 128 + o0);
        float2 p;
        p = bf2x(v0.x); num[0] = fmaf(p.x, ex0, num[0]); num[1] = fmaf(p.y, ex0, num[1]);
        p = bf2x(v0.y); num[2] = fmaf(p.x, ex0, num[2]); num[3] = fmaf(p.y, ex0, num[3]);
        p = bf2x(v0.z); num[4] = fmaf(p.x, ex0, num[4]); num[5] = fmaf(p.y, ex0, num[5]);
        p = bf2x(v0.w); num[6] = fmaf(p.x, ex0, num[6]); num[7] = fmaf(p.y, ex0, num[7]);
        den += ex0;
    }
    float inv = 1.0f / (den + 1e-16f);
    float4 o0v = make_float4(num[0]*inv, num[1]*inv, num[2]*inv, num[3]*inv);
    float4 o1v = make_float4(num[4]*inv, num[5]*inv, num[6]*inv, num[7]*inv);
    *(float4*)(wV + (size_t)dd * 128 + o0)     = o0v;
    *(float4*)(wV + (size_t)dd * 128 + o0 + 4) = o1v;
}

// ---------------------------------------------------------------------------
extern "C" void kernel_launch(void* const* d_in, const int* in_sizes, int n_in,
                              void* d_out, int out_size, void* d_ws, size_t ws_size,
                              hipStream_t stream)
{
    const float* x         = (const float*)d_in[0];
    const int*   edge_idx  = (const int*)d_in[1];
    const float* rrwp      = (const float*)d_in[2];
    const float* edge_attr = (const float*)d_in[3];
    const float* Qw        = (const float*)d_in[4];
    const float* Qb        = (const float*)d_in[5];
    const float* Kw        = (const float*)d_in[6];
    const float* Kb        = (const float*)d_in[7];
    const float* Vw        = (const float*)d_in[8];
    const float* Vb        = (const float*)d_in[9];
    const float* Ew        = (const float*)d_in[10];
    const float* Eb        = (const float*)d_in[11];
    const float* wew       = (const float*)d_in[12];
    const float* web       = (const float*)d_in[13];
    const float* Wang      = (const float*)d_in[14];

    const int* srcI = edge_idx;
    const int* dstI = edge_idx + NE;

    float* wV = (float*)d_out;                       // N * 128
    float* wE = wV + (size_t)N * 128;                // NE * 128

    ushort* EwHiF = (ushort*)d_ws;                   // 34816 bf16
    ushort* EwLoF = EwHiF + 34816;                   // 34816
    ushort* QWHiF = EwLoF + 34816;                   // 49152
    ushort* QWLoF = QWHiF + 49152;                   // 49152
    ushort* VhB = QWLoF + 49152;                     // N*128 bf16
    float* Qh   = (float*)(VhB + (size_t)N * 128);   // N*128 fp32
    float* Kh   = Qh + (size_t)N * 128;
    float* exS  = Kh + (size_t)N * 128;              // NE*8 (position-indexed)
    int* cnt      = (int*)(exS + (size_t)NE * 8);    // N
    int* rowstart = cnt + N;                         // N+1
    int* cursor   = rowstart + (N + 1);              // N
    int* elist    = cursor + N;                      // NE
    int* srcS     = elist + NE;                      // NE
    int* dstS     = srcS + NE;                       // NE
    int* bsum     = dstS + NE;                       // 64

    const int NB_SCAN = (N + 1023) / 1024;           // 49

    hipMemsetAsync(cnt, 0, (size_t)N * sizeof(int), stream);
    hipMemsetAsync(cursor, 0, (size_t)N * sizeof(int), stream);

    prep_w_kernel<<<17, 256, 0, stream>>>(Ew, wew, EwHiF, EwLoF);
    prep_qkvw_kernel<<<24, 256, 0, stream>>>(Qw, Kw, Vw, QWHiF, QWLoF);

    qkv_mfma_kernel<<<(N + QNPB - 1) / QNPB, 256, 0, stream>>>(
        x, rrwp, QWHiF, QWLoF, Qb, Kb, Vb, Wang, Qh, Kh, VhB);

    count_kernel<<<(NE + 255) / 256, 256, 0, stream>>>(dstI, cnt);
    block_scan_kernel<<<NB_SCAN, 1024, 0, stream>>>(cnt, rowstart, bsum);
    scan_totals_kernel<<<1, 64, 0, stream>>>(bsum, NB_SCAN);
    add_offsets_kernel<<<NB_SCAN, 1024, 0, stream>>>(bsum, rowstart);
    scatter_kernel<<<(NE + 255) / 256, 256, 0, stream>>>(
        srcI, dstI, rowstart, cursor, elist, srcS, dstS);

    edge_gemm_kernel<<<NE / EPB, 256, 0, stream>>>(
        edge_attr, elist, srcS, dstS, Qh, Kh, EwHiF, EwLoF, Eb, web, wE, exS);

    wv_kernel<<<N / 16, 256, 0, stream>>>(
        srcS, rowstart, VhB, exS, wV);
}